// Round 1
// baseline (117.669 us; speedup 1.0000x reference)
//
#include <hip/hip_runtime.h>

#define SEQ   2048
#define DM    768
#define ST    100
#define KF    24
#define NC    32      // SEQ / 64
#define KJ    128     // padded state dim (inter-GEMM K)
#define NJ    112     // padded state dim (hloc-GEMM N)

using half8   = __attribute__((ext_vector_type(8))) _Float16;
using float4v = __attribute__((ext_vector_type(4))) float;
using ush8    = __attribute__((ext_vector_type(8))) short;

__device__ __forceinline__ unsigned short f2h(float v) {
    union { _Float16 h; unsigned short u; } cv;
    cv.h = (_Float16)v;
    return cv.u;
}
__device__ __forceinline__ void async16(const void* g, void* l) {
    __builtin_amdgcn_global_load_lds(
        (const __attribute__((address_space(1))) unsigned int*)g,
        (__attribute__((address_space(3))) unsigned int*)l, 16, 0, 0);
}

// ---------------------------------------------------------------------------
// prep: block ranges:
//  [0,144)      Mh[d][k] = fp16(Mi^T)          (64x64 LDS transpose)
//  [144,912)    Xh[s][i] = fp16(x)             (16B stores)
//  [912,1212)   WpT[d][j] = sum_k (C[j,k]+C[j,k+24])*Mf[k,d];  ev[d]
//  [1212]       Apow[dlt][j] (fp32, dlt 0..64); Eh[t][j]=fp16(A^(t+1));
//               Qh[j][i]=fp16(B_j A^(63-i))    (incremental powers only)
// ---------------------------------------------------------------------------
__global__ __launch_bounds__(256) void prep(const float* __restrict__ x,
                                            const float* __restrict__ Mi,
                                            const float* __restrict__ C,
                                            const float* __restrict__ Dv,
                                            const float* __restrict__ Mf,
                                            const float* __restrict__ Av,
                                            const float* __restrict__ Bv,
                                            unsigned short* __restrict__ Mh,
                                            unsigned short* __restrict__ Xh,
                                            float* __restrict__ WpT,
                                            float* __restrict__ evec,
                                            float* __restrict__ Apow,
                                            unsigned short* __restrict__ Eh,
                                            unsigned short* __restrict__ Qh) {
    __shared__ float tl[64][65];
    int bid = blockIdx.x, t = threadIdx.x;
    if (bid < 144) {
        int i0 = (bid / 12) * 64, d0 = (bid % 12) * 64;
        int tx = t & 63, ty = t >> 6;
#pragma unroll
        for (int r = ty; r < 64; r += 4)
            tl[r][tx] = Mi[(i0 + r) * DM + d0 + tx];
        __syncthreads();
#pragma unroll
        for (int r = ty; r < 64; r += 4)
            Mh[(size_t)(d0 + r) * DM + i0 + tx] = f2h(tl[tx][r]);
    } else if (bid < 912) {
        int idx8 = (bid - 144) * 256 + t;              // 8 elems per thread
        int s = idx8 / (DM / 8), i0 = (idx8 % (DM / 8)) * 8;
        const float* xp = x + (size_t)s * DM + i0;
        float4 v0 = *(const float4*)xp;
        float4 v1 = *(const float4*)(xp + 4);
        float av[8] = {v0.x, v0.y, v0.z, v0.w, v1.x, v1.y, v1.z, v1.w};
        ush8 hh;
#pragma unroll
        for (int q = 0; q < 8; ++q) hh[q] = (short)f2h(av[q]);
        *(ush8*)(Xh + (size_t)s * DM + i0) = hh;
    } else if (bid < 1212) {
        int tid = (bid - 912) * 256 + t;
        if (tid < ST * DM) {
            int d = tid / ST, j = tid % ST;
            float s = 0.f;
#pragma unroll
            for (int k = 0; k < KF; ++k)
                s += (C[j * 2 * KF + k] + C[j * 2 * KF + KF + k]) * Mf[k * DM + d];
            WpT[tid] = s;
        }
        if (tid < DM) {
            float s = 0.f;
#pragma unroll
            for (int k = 0; k < KF; ++k)
                s += (Dv[k] + Dv[KF + k]) * Mf[k * DM + tid];
            evec[tid] = s;
        }
    } else {
        if (t < KJ) {
            bool ja = (t < ST);
            float a = ja ? Av[t] : 0.f;
            float b = ja ? Bv[t] : 0.f;
            float p = 1.f;                             // p = A^dlt
            for (int dlt = 0; dlt < 64; ++dlt) {
                if (ja) Apow[dlt * ST + t] = p;
                if (t < NJ) Qh[t * 64 + 63 - dlt] = f2h(b * p);
                p *= a;                                // p = A^(dlt+1)
                Eh[dlt * KJ + t] = f2h(p);
            }
            if (ja) Apow[64 * ST + t] = p;             // A^64
        }
    }
}

// ---------------------------------------------------------------------------
// MFMA GEMM (fp16, no split, no atomics): ut[d][s] = Mh[d][:] . Xh[s][:].
// 64x64 tiles, 384 blocks, BK=64 (12 iters), rotate-swizzled LDS
// (chunk q' = (q + row) & 7), async16 staging, mfma_f32_16x16x32_f16.
// Double-buffered: stage(next) issued BEFORE ds_read+MFMA of cur; ONE
// __syncthreads per iter (its implicit vmcnt(0) drains the next-tile loads
// after they've had the whole compute window to fly).
// ---------------------------------------------------------------------------
__global__ __launch_bounds__(256) void gemm_mfma(const unsigned short* __restrict__ Mh,
                                                 const unsigned short* __restrict__ Xh,
                                                 float* __restrict__ ut) {
    __shared__ unsigned short As[2][64 * 64];
    __shared__ unsigned short Bs[2][64 * 64];
    int t = threadIdx.x;
    int tile = blockIdx.x;
    int d0 = (tile % (DM / 64)) * 64;
    int s0 = (tile / (DM / 64)) * 64;
    int wave = t >> 6, lane = t & 63;
    int m16 = lane & 15, quad = lane >> 4;
    // staging slot L -> (row=L>>3, q'=L&7); source chunk q=(q'-row)&7
    int r0 = t >> 3,         q0 = ((t & 7) - r0) & 7;
    int r1 = (t + 256) >> 3, q1 = (((t + 256) & 7) - r1) & 7;
    float4v acc[4];
#pragma unroll
    for (int nt = 0; nt < 4; ++nt) acc[nt] = (float4v){0.f, 0.f, 0.f, 0.f};

#define STAGE(buf, kk0)                                                                     \
    async16(&Mh[(size_t)(d0 + r0) * DM + (kk0) + q0 * 8], &As[buf][(size_t)t * 8]);         \
    async16(&Xh[(size_t)(s0 + r0) * DM + (kk0) + q0 * 8], &Bs[buf][(size_t)t * 8]);         \
    async16(&Mh[(size_t)(d0 + r1) * DM + (kk0) + q1 * 8], &As[buf][(size_t)(t + 256) * 8]); \
    async16(&Xh[(size_t)(s0 + r1) * DM + (kk0) + q1 * 8], &Bs[buf][(size_t)(t + 256) * 8]);

    STAGE(0, 0);
    __syncthreads();
    int cur = 0;
    int arow = wave * 16 + m16;
    for (int k0 = 0; k0 < DM; k0 += 64) {
        if (k0 + 64 < DM) { STAGE(cur ^ 1, k0 + 64); }
        half8 af[2], bf[4][2];
#pragma unroll
        for (int h = 0; h < 2; ++h)
            af[h] = *(half8*)&As[cur][arow * 64 + (((h * 4 + quad) + arow) & 7) * 8];
#pragma unroll
        for (int nt = 0; nt < 4; ++nt) {
            int brow = nt * 16 + m16;
#pragma unroll
            for (int h = 0; h < 2; ++h)
                bf[nt][h] = *(half8*)&Bs[cur][brow * 64 + (((h * 4 + quad) + brow) & 7) * 8];
        }
#pragma unroll
        for (int h = 0; h < 2; ++h)
#pragma unroll
            for (int nt = 0; nt < 4; ++nt)
                acc[nt] = __builtin_amdgcn_mfma_f32_16x16x32_f16(af[h], bf[nt][h], acc[nt], 0, 0, 0);
        __syncthreads();
        cur ^= 1;
    }
#undef STAGE
#pragma unroll
    for (int nt = 0; nt < 4; ++nt) {
        int dd = d0 + wave * 16 + quad * 4;
        int ss = s0 + nt * 16 + m16;
#pragma unroll
        for (int i = 0; i < 4; ++i)
            ut[(size_t)(dd + i) * SEQ + ss] = acc[nt][i];
    }
}

// ---------------------------------------------------------------------------
// scanf_k: fused Kmat + hloc GEMM + chunk scan + G write + intra Toeplitz.
// Block = 2 channels (384 blocks, 256 threads). ut read, then y written
// in place into ut (block-private rows).
// P3 now uses all 256 threads (balanced lo/hi output octets per wave) and
// reads inputs from LDS ul[] staged for free during P1's global loads.
// ---------------------------------------------------------------------------
__global__ __launch_bounds__(256) void scanf_k(float* ut,
                                               const unsigned short* __restrict__ Qh,
                                               const float* __restrict__ WpT,
                                               const float* __restrict__ Apow,
                                               const float* __restrict__ Bv,
                                               const float* __restrict__ evec,
                                               unsigned short* __restrict__ Gh) {
    __shared__ float hl[64][120];
    __shared__ float kk[128];
    __shared__ float ul[2][32][65];   // chunk inputs, pad-65 -> bank=(c+i)%32
    int t = threadIdx.x;
    int m0 = blockIdx.x * 64;
    int d0 = blockIdx.x * 2;
    // ---- P0: Kmat taps for this block's 2 channels ----
    if (t < 128) {
        int dlt = t & 63, dloc = t >> 6;
        const float* wrow = WpT + (d0 + dloc) * ST;
        float s = 0.f;
        for (int j = 0; j < ST; ++j)
            s = fmaf(Bv[j] * Apow[dlt * ST + j], wrow[j], s);
        kk[t] = s;
    }
    // ---- P1: hloc = ut rows @ Q^T (fp16 MFMA); stash u rows into ul ----
    int wave = t >> 6, lane = t & 63;
    int m16 = lane & 15, quad = lane >> 4;
    {
        int r = wave * 16 + m16;
        float4v acc[7];
#pragma unroll
        for (int nt = 0; nt < 7; ++nt) acc[nt] = (float4v){0.f, 0.f, 0.f, 0.f};
#pragma unroll
        for (int ks = 0; ks < 2; ++ks) {
            size_t ao = (size_t)(m0 + r) * 64 + ks * 32 + quad * 8;
            float4 a0 = *(const float4*)(ut + ao);
            float4 a1 = *(const float4*)(ut + ao + 4);
            *(float4*)&ul[r >> 5][r & 31][ks * 32 + quad * 8]     = a0;
            *(float4*)&ul[r >> 5][r & 31][ks * 32 + quad * 8 + 4] = a1;
            float av[8] = {a0.x, a0.y, a0.z, a0.w, a1.x, a1.y, a1.z, a1.w};
            half8 ah;
#pragma unroll
            for (int q = 0; q < 8; ++q) ah[q] = (_Float16)av[q];
#pragma unroll
            for (int nt = 0; nt < 7; ++nt) {
                half8 bh = *(const half8*)(Qh + (nt * 16 + m16) * 64 + ks * 32 + quad * 8);
                acc[nt] = __builtin_amdgcn_mfma_f32_16x16x32_f16(ah, bh, acc[nt], 0, 0, 0);
            }
        }
#pragma unroll
        for (int nt = 0; nt < 7; ++nt)
#pragma unroll
            for (int i = 0; i < 4; ++i)
                hl[wave * 16 + quad * 4 + i][nt * 16 + m16] = acc[nt][i];
    }
    __syncthreads();
    // ---- P2: inter-chunk scan + G = fp16(w * hs) ----
    {
        int j = t & 127, dloc = t >> 7;
        int d = d0 + dloc;
        bool ja = (j < ST);
        float a64 = ja ? Apow[64 * ST + j] : 0.f;
        float w   = ja ? WpT[d * ST + j] : 0.f;
        float hs = 0.f;
        for (int c = 0; c < NC; ++c) {
            Gh[((size_t)c * DM + d) * KJ + j] = f2h(w * hs);
            float add = ja ? hl[dloc * 32 + c][j] : 0.f;
            hs = fmaf(a64, hs, add);
        }
    }
    // ---- P3: intra Toeplitz, all 256 threads. Thread = (d,c) pair; wave q
    // computes balanced output octets lo=[8q,8q+8) and hi=[56-8q,64-8q). ----
    {
        int q = wave;
        int p = t & 63;
        int dloc = p >> 5, c = p & 31;
        int d = d0 + dloc;
        int lo0 = q * 8, hi0 = (7 - q) * 8;
        const float* kt = &kk[dloc * 64];
        const float* us = &ul[dloc][c][0];
        float e = evec[d];
        float ylo[8], yhi[8];
#pragma unroll
        for (int z = 0; z < 8; ++z) {
            ylo[z] = e * us[lo0 + z];
            yhi[z] = e * us[hi0 + z];
        }
        for (int i = 0; i < lo0; ++i) {          // wave-uniform bound
            float u = us[i];
#pragma unroll
            for (int z = 0; z < 8; ++z) {
                ylo[z] = fmaf(kt[lo0 + z - i], u, ylo[z]);
                yhi[z] = fmaf(kt[hi0 + z - i], u, yhi[z]);
            }
        }
#pragma unroll
        for (int zi = 0; zi < 8; ++zi) {         // triangular, lo block
            float u = us[lo0 + zi];
#pragma unroll
            for (int z = zi; z < 8; ++z)
                ylo[z] = fmaf(kt[z - zi], u, ylo[z]);
#pragma unroll
            for (int z = 0; z < 8; ++z)
                yhi[z] = fmaf(kt[hi0 - lo0 + z - zi], u, yhi[z]);
        }
        for (int i = lo0 + 8; i < hi0; ++i) {    // wave-uniform bound
            float u = us[i];
#pragma unroll
            for (int z = 0; z < 8; ++z)
                yhi[z] = fmaf(kt[hi0 + z - i], u, yhi[z]);
        }
#pragma unroll
        for (int zi = 0; zi < 8; ++zi) {         // triangular, hi block
            float u = us[hi0 + zi];
#pragma unroll
            for (int z = zi; z < 8; ++z)
                yhi[z] = fmaf(kt[z - zi], u, yhi[z]);
        }
        size_t off = (size_t)d * SEQ + c * 64;
        *(float4*)(ut + off + lo0)     = make_float4(ylo[0], ylo[1], ylo[2], ylo[3]);
        *(float4*)(ut + off + lo0 + 4) = make_float4(ylo[4], ylo[5], ylo[6], ylo[7]);
        *(float4*)(ut + off + hi0)     = make_float4(yhi[0], yhi[1], yhi[2], yhi[3]);
        *(float4*)(ut + off + hi0 + 4) = make_float4(yhi[4], yhi[5], yhi[6], yhi[7]);
    }
}

// ---------------------------------------------------------------------------
// inter: out[c*64+t][d] = (E @ G_c)[t][d] + yintra[d][c*64+t]
// Block = (chunk c, 64-wide d tile): M=64, N=64, K=128 fp16, 4 waves.
// ---------------------------------------------------------------------------
__global__ __launch_bounds__(256) void inter(const unsigned short* __restrict__ Eh,
                                             const unsigned short* __restrict__ Gh,
                                             const float* __restrict__ yintra,
                                             float* __restrict__ out) {
    __shared__ float yl[64][65];    // pad 65: staging writes 2-way (free), was 8-way
    int c = blockIdx.x;
    int d0 = blockIdx.y * 64;
    int t = threadIdx.x;
#pragma unroll
    for (int it = 0; it < 4; ++it) {
        int idx = t + it * 256;
        int row = idx >> 4, col4 = (idx & 15) * 4;
        float4 v = *(const float4*)&yintra[(size_t)(d0 + row) * SEQ + c * 64 + col4];
        yl[col4 + 0][row] = v.x;
        yl[col4 + 1][row] = v.y;
        yl[col4 + 2][row] = v.z;
        yl[col4 + 3][row] = v.w;
    }
    __syncthreads();
    int wave = t >> 6, lane = t & 63;
    int wn = wave * 16;
    int m16 = lane & 15, quad = lane >> 4;
    float4v acc[4];
#pragma unroll
    for (int mt = 0; mt < 4; ++mt) acc[mt] = (float4v){0.f, 0.f, 0.f, 0.f};
#pragma unroll
    for (int ks = 0; ks < 4; ++ks) {
        half8 bh = *(const half8*)(Gh + ((size_t)c * DM + d0 + wn + m16) * KJ + ks * 32 + quad * 8);
#pragma unroll
        for (int mt = 0; mt < 4; ++mt) {
            half8 ah = *(const half8*)(Eh + (mt * 16 + m16) * KJ + ks * 32 + quad * 8);
            acc[mt] = __builtin_amdgcn_mfma_f32_16x16x32_f16(ah, bh, acc[mt], 0, 0, 0);
        }
    }
#pragma unroll
    for (int mt = 0; mt < 4; ++mt) {
        int tt = mt * 16 + quad * 4;
        int dcol = wn + m16;
#pragma unroll
        for (int i = 0; i < 4; ++i) {
            float v = acc[mt][i] + yl[tt + i][dcol];
            out[(size_t)(c * 64 + tt + i) * DM + d0 + dcol] = v;
        }
    }
}

extern "C" void kernel_launch(void* const* d_in, const int* in_sizes, int n_in,
                              void* d_out, int out_size, void* d_ws, size_t ws_size,
                              hipStream_t stream) {
    const float* x  = (const float*)d_in[0];
    const float* Mi = (const float*)d_in[2];
    const float* Mf = (const float*)d_in[3];
    const float* Av = (const float*)d_in[4];
    const float* Bv = (const float*)d_in[5];
    const float* C  = (const float*)d_in[6];
    const float* Dv = (const float*)d_in[7];
    float* out = (float*)d_out;

    float* ut   = (float*)d_ws;                           // 768*2048 f32
    float* WpT  = ut + (size_t)DM * SEQ;                  // 768*100
    float* ev   = WpT + DM * ST;                          // 768
    float* Apow = ev + DM;                                // 65*100
    unsigned short* Mh = (unsigned short*)(Apow + 65 * ST);   // 768*768 fp16
    unsigned short* Xh = Mh + (size_t)DM * DM;            // 2048*768 fp16
    unsigned short* Eh = Xh + (size_t)SEQ * DM;           // 64*128 fp16
    unsigned short* Qh = Eh + 64 * KJ;                    // 112*64 fp16
    unsigned short* Gh = Qh + NJ * 64;                    // 32*768*128 fp16

    prep<<<1213, 256, 0, stream>>>(x, Mi, C, Dv, Mf, Av, Bv, Mh, Xh,
                                   WpT, ev, Apow, Eh, Qh);
    gemm_mfma<<<(DM / 64) * (SEQ / 64), 256, 0, stream>>>(Mh, Xh, ut);
    scanf_k<<<384, 256, 0, stream>>>(ut, Qh, WpT, Apow, Bv, ev, Gh);
    inter<<<dim3(NC, DM / 64), 256, 0, stream>>>(Eh, Gh, ut, out);
}

// Round 2
// 115.348 us; speedup vs baseline: 1.0201x; 1.0201x over previous
//
#include <hip/hip_runtime.h>

#define SEQ   2048
#define DM    768
#define ST    100
#define KF    24
#define NC    32      // SEQ / 64
#define KJ    128     // padded state dim (inter-GEMM K)
#define NJ    112     // padded state dim (hloc-GEMM N)

using half8   = __attribute__((ext_vector_type(8))) _Float16;
using float4v = __attribute__((ext_vector_type(4))) float;
using ush8    = __attribute__((ext_vector_type(8))) short;

__device__ __forceinline__ unsigned short f2h(float v) {
    union { _Float16 h; unsigned short u; } cv;
    cv.h = (_Float16)v;
    return cv.u;
}
__device__ __forceinline__ void async16(const void* g, void* l) {
    __builtin_amdgcn_global_load_lds(
        (const __attribute__((address_space(1))) unsigned int*)g,
        (__attribute__((address_space(3))) unsigned int*)l, 16, 0, 0);
}

// ---------------------------------------------------------------------------
// prep: block ranges:
//  [0,144)      Mh[d][k] = fp16(Mi^T)          (64x64 LDS transpose)
//  [144,912)    Xh[s][i] = fp16(x)             (16B stores)
//  [912,1212)   WpT[d][j] = sum_k (C[j,k]+C[j,k+24])*Mf[k,d];  ev[d]
//  [1212]       Apow[dlt][j] (fp32); Eh; Qh
//  [1213,1405)  Kt[d][dlt] = sum_j Bv[j] A^dlt W[d][j]  (4 channels/block)
// ---------------------------------------------------------------------------
__global__ __launch_bounds__(256) void prep(const float* __restrict__ x,
                                            const float* __restrict__ Mi,
                                            const float* __restrict__ C,
                                            const float* __restrict__ Dv,
                                            const float* __restrict__ Mf,
                                            const float* __restrict__ Av,
                                            const float* __restrict__ Bv,
                                            unsigned short* __restrict__ Mh,
                                            unsigned short* __restrict__ Xh,
                                            float* __restrict__ WpT,
                                            float* __restrict__ evec,
                                            float* __restrict__ Apow,
                                            unsigned short* __restrict__ Eh,
                                            unsigned short* __restrict__ Qh,
                                            float* __restrict__ Kt) {
    __shared__ float tl[64][65];
    __shared__ float Wl[4][100];
    __shared__ float ApB[100][65];
    int bid = blockIdx.x, t = threadIdx.x;
    if (bid < 144) {
        int i0 = (bid / 12) * 64, d0 = (bid % 12) * 64;
        int tx = t & 63, ty = t >> 6;
#pragma unroll
        for (int r = ty; r < 64; r += 4)
            tl[r][tx] = Mi[(i0 + r) * DM + d0 + tx];
        __syncthreads();
#pragma unroll
        for (int r = ty; r < 64; r += 4)
            Mh[(size_t)(d0 + r) * DM + i0 + tx] = f2h(tl[tx][r]);
    } else if (bid < 912) {
        int idx8 = (bid - 144) * 256 + t;              // 8 elems per thread
        int s = idx8 / (DM / 8), i0 = (idx8 % (DM / 8)) * 8;
        const float* xp = x + (size_t)s * DM + i0;
        float4 v0 = *(const float4*)xp;
        float4 v1 = *(const float4*)(xp + 4);
        float av[8] = {v0.x, v0.y, v0.z, v0.w, v1.x, v1.y, v1.z, v1.w};
        ush8 hh;
#pragma unroll
        for (int q = 0; q < 8; ++q) hh[q] = (short)f2h(av[q]);
        *(ush8*)(Xh + (size_t)s * DM + i0) = hh;
    } else if (bid < 1212) {
        int tid = (bid - 912) * 256 + t;
        if (tid < ST * DM) {
            int d = tid / ST, j = tid % ST;
            float s = 0.f;
#pragma unroll
            for (int k = 0; k < KF; ++k)
                s += (C[j * 2 * KF + k] + C[j * 2 * KF + KF + k]) * Mf[k * DM + d];
            WpT[tid] = s;
        }
        if (tid < DM) {
            float s = 0.f;
#pragma unroll
            for (int k = 0; k < KF; ++k)
                s += (Dv[k] + Dv[KF + k]) * Mf[k * DM + tid];
            evec[tid] = s;
        }
    } else if (bid == 1212) {
        if (t < KJ) {
            bool ja = (t < ST);
            float a = ja ? Av[t] : 0.f;
            float b = ja ? Bv[t] : 0.f;
            float p = 1.f;                             // p = A^dlt
            for (int dlt = 0; dlt < 64; ++dlt) {
                if (ja) Apow[dlt * ST + t] = p;
                if (t < NJ) Qh[t * 64 + 63 - dlt] = f2h(b * p);
                p *= a;                                // p = A^(dlt+1)
                Eh[dlt * KJ + t] = f2h(p);
            }
            if (ja) Apow[64 * ST + t] = p;             // A^64
        }
    } else {
        // Kt for channels [d0k, d0k+4): Kt[d][dlt] = sum_j W[d][j]*Bv[j]*A_j^dlt
        int d0k = (bid - 1213) * 4;
        for (int idx = t; idx < 4 * ST; idx += 256) {
            int dl = idx / ST, j = idx % ST;
            float s = 0.f;
#pragma unroll
            for (int k = 0; k < KF; ++k)
                s += (C[j * 2 * KF + k] + C[j * 2 * KF + KF + k]) * Mf[k * DM + d0k + dl];
            Wl[dl][j] = s;
        }
        if (t < ST) {
            float a = Av[t], p = Bv[t];
            for (int dlt = 0; dlt < 64; ++dlt) { ApB[t][dlt] = p; p *= a; }
        }
        __syncthreads();
        int dl = t >> 6, dlt = t & 63;
        float s = 0.f;
        for (int j = 0; j < ST; ++j)
            s = fmaf(Wl[dl][j], ApB[j][dlt], s);
        Kt[(d0k + dl) * 64 + dlt] = s;
    }
}

// ---------------------------------------------------------------------------
// MFMA GEMM: ut[d][s] = Mh[d][:] . Xh[s][:].  64x64 tiles, 384 blocks,
// BK=64 (12 iters), rotate-swizzled LDS, async16 staging.
// 3-buffer pipeline, 2 tiles in flight, counted s_waitcnt vmcnt(4) (never 0
// in steady state), raw s_barrier, lgkmcnt(0) before barrier so a buffer is
// never overwritten while a slow wave's ds_reads are in flight.
// ---------------------------------------------------------------------------
__global__ __launch_bounds__(256) void gemm_mfma(const unsigned short* __restrict__ Mh,
                                                 const unsigned short* __restrict__ Xh,
                                                 float* __restrict__ ut) {
    __shared__ unsigned short As[3][64 * 64];
    __shared__ unsigned short Bs[3][64 * 64];
    int t = threadIdx.x;
    int tile = blockIdx.x;
    int d0 = (tile % (DM / 64)) * 64;
    int s0 = (tile / (DM / 64)) * 64;
    int wave = t >> 6, lane = t & 63;
    int m16 = lane & 15, quad = lane >> 4;
    // staging slot L -> (row=L>>3, q'=L&7); source chunk q=(q'-row)&7
    int r0 = t >> 3,         q0 = ((t & 7) - r0) & 7;
    int r1 = (t + 256) >> 3, q1 = (((t + 256) & 7) - r1) & 7;
    float4v acc[4];
#pragma unroll
    for (int nt = 0; nt < 4; ++nt) acc[nt] = (float4v){0.f, 0.f, 0.f, 0.f};

#define STAGE(buf, kk0)                                                                     \
    async16(&Mh[(size_t)(d0 + r0) * DM + (kk0) + q0 * 8], &As[buf][(size_t)t * 8]);         \
    async16(&Xh[(size_t)(s0 + r0) * DM + (kk0) + q0 * 8], &Bs[buf][(size_t)t * 8]);         \
    async16(&Mh[(size_t)(d0 + r1) * DM + (kk0) + q1 * 8], &As[buf][(size_t)(t + 256) * 8]); \
    async16(&Xh[(size_t)(s0 + r1) * DM + (kk0) + q1 * 8], &Bs[buf][(size_t)(t + 256) * 8]);

    STAGE(0, 0);            // tile 0 -> 4 vmem ops
    STAGE(1, 64);           // tile 1 -> 8 in flight
    int arow = wave * 16 + m16;
#pragma unroll
    for (int it = 0; it < 12; ++it) {
        const int cur = it % 3;
        const int sb  = (it + 2) % 3;
        asm volatile("s_waitcnt lgkmcnt(0)" ::: "memory");   // prior ds_reads done (free in steady state)
        if (it < 10) asm volatile("s_waitcnt vmcnt(4)" ::: "memory");  // tile `it` landed, tile it+1 flying
        else         asm volatile("s_waitcnt vmcnt(0)" ::: "memory");  // epilogue drain
        __builtin_amdgcn_s_barrier();
        if (it < 10) { STAGE(sb, it * 64 + 128); }           // tile it+2 into distinct buffer
        half8 af[2], bf[4][2];
#pragma unroll
        for (int h = 0; h < 2; ++h)
            af[h] = *(half8*)&As[cur][arow * 64 + (((h * 4 + quad) + arow) & 7) * 8];
#pragma unroll
        for (int nt = 0; nt < 4; ++nt) {
            int brow = nt * 16 + m16;
#pragma unroll
            for (int h = 0; h < 2; ++h)
                bf[nt][h] = *(half8*)&Bs[cur][brow * 64 + (((h * 4 + quad) + brow) & 7) * 8];
        }
#pragma unroll
        for (int h = 0; h < 2; ++h)
#pragma unroll
            for (int nt = 0; nt < 4; ++nt)
                acc[nt] = __builtin_amdgcn_mfma_f32_16x16x32_f16(af[h], bf[nt][h], acc[nt], 0, 0, 0);
    }
#undef STAGE
#pragma unroll
    for (int nt = 0; nt < 4; ++nt) {
        int dd = d0 + wave * 16 + quad * 4;
        int ss = s0 + nt * 16 + m16;
#pragma unroll
        for (int i = 0; i < 4; ++i)
            ut[(size_t)(dd + i) * SEQ + ss] = acc[nt][i];
    }
}

// ---------------------------------------------------------------------------
// scanf_k: fused hloc GEMM + chunk scan + G write + intra Toeplitz.
// Block = 2 channels (384 blocks, 256 threads). Kmat taps now precomputed
// in prep (Kt) -> P0 is a single coalesced load.
// ---------------------------------------------------------------------------
__global__ __launch_bounds__(256) void scanf_k(float* ut,
                                               const unsigned short* __restrict__ Qh,
                                               const float* __restrict__ WpT,
                                               const float* __restrict__ Apow,
                                               const float* __restrict__ evec,
                                               unsigned short* __restrict__ Gh,
                                               const float* __restrict__ Kt) {
    __shared__ float hl[64][120];
    __shared__ float kk[128];
    __shared__ float ul[2][32][65];   // chunk inputs, pad-65 -> bank=(c+i)%32
    int t = threadIdx.x;
    int m0 = blockIdx.x * 64;
    int d0 = blockIdx.x * 2;
    // ---- P0: load precomputed Kmat taps ----
    if (t < 128)
        kk[t] = Kt[(d0 + (t >> 6)) * 64 + (t & 63)];
    // ---- P1: hloc = ut rows @ Q^T (fp16 MFMA); stash u rows into ul ----
    int wave = t >> 6, lane = t & 63;
    int m16 = lane & 15, quad = lane >> 4;
    {
        int r = wave * 16 + m16;
        float4v acc[7];
#pragma unroll
        for (int nt = 0; nt < 7; ++nt) acc[nt] = (float4v){0.f, 0.f, 0.f, 0.f};
#pragma unroll
        for (int ks = 0; ks < 2; ++ks) {
            size_t ao = (size_t)(m0 + r) * 64 + ks * 32 + quad * 8;
            float4 a0 = *(const float4*)(ut + ao);
            float4 a1 = *(const float4*)(ut + ao + 4);
            *(float4*)&ul[r >> 5][r & 31][ks * 32 + quad * 8]     = a0;
            *(float4*)&ul[r >> 5][r & 31][ks * 32 + quad * 8 + 4] = a1;
            float av[8] = {a0.x, a0.y, a0.z, a0.w, a1.x, a1.y, a1.z, a1.w};
            half8 ah;
#pragma unroll
            for (int q = 0; q < 8; ++q) ah[q] = (_Float16)av[q];
#pragma unroll
            for (int nt = 0; nt < 7; ++nt) {
                half8 bh = *(const half8*)(Qh + (nt * 16 + m16) * 64 + ks * 32 + quad * 8);
                acc[nt] = __builtin_amdgcn_mfma_f32_16x16x32_f16(ah, bh, acc[nt], 0, 0, 0);
            }
        }
#pragma unroll
        for (int nt = 0; nt < 7; ++nt)
#pragma unroll
            for (int i = 0; i < 4; ++i)
                hl[wave * 16 + quad * 4 + i][nt * 16 + m16] = acc[nt][i];
    }
    __syncthreads();
    // ---- P2: inter-chunk scan + G = fp16(w * hs) ----
    {
        int j = t & 127, dloc = t >> 7;
        int d = d0 + dloc;
        bool ja = (j < ST);
        float a64 = ja ? Apow[64 * ST + j] : 0.f;
        float w   = ja ? WpT[d * ST + j] : 0.f;
        float hs = 0.f;
        for (int c = 0; c < NC; ++c) {
            Gh[((size_t)c * DM + d) * KJ + j] = f2h(w * hs);
            float add = ja ? hl[dloc * 32 + c][j] : 0.f;
            hs = fmaf(a64, hs, add);
        }
    }
    // ---- P3: intra Toeplitz, all 256 threads. Thread = (d,c) pair; wave q
    // computes balanced output octets lo=[8q,8q+8) and hi=[56-8q,64-8q). ----
    {
        int q = wave;
        int p = t & 63;
        int dloc = p >> 5, c = p & 31;
        int d = d0 + dloc;
        int lo0 = q * 8, hi0 = (7 - q) * 8;
        const float* kt = &kk[dloc * 64];
        const float* us = &ul[dloc][c][0];
        float e = evec[d];
        float ylo[8], yhi[8];
#pragma unroll
        for (int z = 0; z < 8; ++z) {
            ylo[z] = e * us[lo0 + z];
            yhi[z] = e * us[hi0 + z];
        }
        for (int i = 0; i < lo0; ++i) {          // wave-uniform bound
            float u = us[i];
#pragma unroll
            for (int z = 0; z < 8; ++z) {
                ylo[z] = fmaf(kt[lo0 + z - i], u, ylo[z]);
                yhi[z] = fmaf(kt[hi0 + z - i], u, yhi[z]);
            }
        }
#pragma unroll
        for (int zi = 0; zi < 8; ++zi) {         // triangular, lo block
            float u = us[lo0 + zi];
#pragma unroll
            for (int z = zi; z < 8; ++z)
                ylo[z] = fmaf(kt[z - zi], u, ylo[z]);
#pragma unroll
            for (int z = 0; z < 8; ++z)
                yhi[z] = fmaf(kt[hi0 - lo0 + z - zi], u, yhi[z]);
        }
        for (int i = lo0 + 8; i < hi0; ++i) {    // wave-uniform bound
            float u = us[i];
#pragma unroll
            for (int z = 0; z < 8; ++z)
                yhi[z] = fmaf(kt[hi0 + z - i], u, yhi[z]);
        }
#pragma unroll
        for (int zi = 0; zi < 8; ++zi) {         // triangular, hi block
            float u = us[hi0 + zi];
#pragma unroll
            for (int z = zi; z < 8; ++z)
                yhi[z] = fmaf(kt[z - zi], u, yhi[z]);
        }
        size_t off = (size_t)d * SEQ + c * 64;
        *(float4*)(ut + off + lo0)     = make_float4(ylo[0], ylo[1], ylo[2], ylo[3]);
        *(float4*)(ut + off + lo0 + 4) = make_float4(ylo[4], ylo[5], ylo[6], ylo[7]);
        *(float4*)(ut + off + hi0)     = make_float4(yhi[0], yhi[1], yhi[2], yhi[3]);
        *(float4*)(ut + off + hi0 + 4) = make_float4(yhi[4], yhi[5], yhi[6], yhi[7]);
    }
}

// ---------------------------------------------------------------------------
// inter: out[c*64+t][d] = (E @ G_c)[t][d] + yintra[d][c*64+t]
// Block = (chunk c, 64-wide d tile): M=64, N=64, K=128 fp16, 4 waves.
// ---------------------------------------------------------------------------
__global__ __launch_bounds__(256) void inter(const unsigned short* __restrict__ Eh,
                                             const unsigned short* __restrict__ Gh,
                                             const float* __restrict__ yintra,
                                             float* __restrict__ out) {
    __shared__ float yl[64][65];    // pad 65: staging writes 2-way (free)
    int c = blockIdx.x;
    int d0 = blockIdx.y * 64;
    int t = threadIdx.x;
#pragma unroll
    for (int it = 0; it < 4; ++it) {
        int idx = t + it * 256;
        int row = idx >> 4, col4 = (idx & 15) * 4;
        float4 v = *(const float4*)&yintra[(size_t)(d0 + row) * SEQ + c * 64 + col4];
        yl[col4 + 0][row] = v.x;
        yl[col4 + 1][row] = v.y;
        yl[col4 + 2][row] = v.z;
        yl[col4 + 3][row] = v.w;
    }
    __syncthreads();
    int wave = t >> 6, lane = t & 63;
    int wn = wave * 16;
    int m16 = lane & 15, quad = lane >> 4;
    float4v acc[4];
#pragma unroll
    for (int mt = 0; mt < 4; ++mt) acc[mt] = (float4v){0.f, 0.f, 0.f, 0.f};
#pragma unroll
    for (int ks = 0; ks < 4; ++ks) {
        half8 bh = *(const half8*)(Gh + ((size_t)c * DM + d0 + wn + m16) * KJ + ks * 32 + quad * 8);
#pragma unroll
        for (int mt = 0; mt < 4; ++mt) {
            half8 ah = *(const half8*)(Eh + (mt * 16 + m16) * KJ + ks * 32 + quad * 8);
            acc[mt] = __builtin_amdgcn_mfma_f32_16x16x32_f16(ah, bh, acc[mt], 0, 0, 0);
        }
    }
#pragma unroll
    for (int mt = 0; mt < 4; ++mt) {
        int tt = mt * 16 + quad * 4;
        int dcol = wn + m16;
#pragma unroll
        for (int i = 0; i < 4; ++i) {
            float v = acc[mt][i] + yl[tt + i][dcol];
            out[(size_t)(c * 64 + tt + i) * DM + d0 + dcol] = v;
        }
    }
}

extern "C" void kernel_launch(void* const* d_in, const int* in_sizes, int n_in,
                              void* d_out, int out_size, void* d_ws, size_t ws_size,
                              hipStream_t stream) {
    const float* x  = (const float*)d_in[0];
    const float* Mi = (const float*)d_in[2];
    const float* Mf = (const float*)d_in[3];
    const float* Av = (const float*)d_in[4];
    const float* Bv = (const float*)d_in[5];
    const float* C  = (const float*)d_in[6];
    const float* Dv = (const float*)d_in[7];
    float* out = (float*)d_out;

    float* ut   = (float*)d_ws;                           // 768*2048 f32
    float* WpT  = ut + (size_t)DM * SEQ;                  // 768*100
    float* ev   = WpT + DM * ST;                          // 768
    float* Apow = ev + DM;                                // 65*100
    unsigned short* Mh = (unsigned short*)(Apow + 65 * ST);   // 768*768 fp16
    unsigned short* Xh = Mh + (size_t)DM * DM;            // 2048*768 fp16
    unsigned short* Eh = Xh + (size_t)SEQ * DM;           // 64*128 fp16
    unsigned short* Qh = Eh + 64 * KJ;                    // 112*64 fp16
    unsigned short* Gh = Qh + NJ * 64;                    // 32*768*128 fp16
    float* Kt = (float*)(Gh + (size_t)NC * DM * KJ);      // 768*64 f32

    prep<<<1405, 256, 0, stream>>>(x, Mi, C, Dv, Mf, Av, Bv, Mh, Xh,
                                   WpT, ev, Apow, Eh, Qh, Kt);
    gemm_mfma<<<(DM / 64) * (SEQ / 64), 256, 0, stream>>>(Mh, Xh, ut);
    scanf_k<<<384, 256, 0, stream>>>(ut, Qh, WpT, Apow, ev, Gh, Kt);
    inter<<<dim3(NC, DM / 64), 256, 0, stream>>>(Eh, Gh, ut, out);
}